// Round 2
// 1710.549 us; speedup vs baseline: 1.1492x; 1.1492x over previous
//
#include <hip/hip_runtime.h>
#include <hip/hip_bf16.h>

#define DMODEL 1024
#define NHEAD 16
#define DHEAD 64
#define NLAYER 4
#define DFF_ 4096
#define VOCAB 32000
#define SEQ 1024
#define BATCH 2
#define MTOK (BATCH*SEQ)

typedef __bf16 bf16x8 __attribute__((ext_vector_type(8)));
typedef __bf16 bf16x4v __attribute__((ext_vector_type(4)));
typedef float f32x4 __attribute__((ext_vector_type(4)));
using bf16 = __hip_bfloat16;

__device__ __forceinline__ void async_copy16(const void* g, void* l) {
  __builtin_amdgcn_global_load_lds(
      (__attribute__((address_space(1))) void*)(g),
      (__attribute__((address_space(3))) void*)(l),
      16, 0, 0);
}

// ---------------- weight conversion kernels ----------------

__global__ __launch_bounds__(256) void convert_bf16_kernel(
    const float* __restrict__ in, bf16* __restrict__ out, long n) {
  long i = ((long)blockIdx.x * 256 + threadIdx.x) * 4;
  if (i >= n) return;
  float4 v = *(const float4*)(in + i);
  bf16x4v p;
  p[0] = (__bf16)v.x; p[1] = (__bf16)v.y; p[2] = (__bf16)v.z; p[3] = (__bf16)v.w;
  *(bf16x4v*)((__bf16*)out + i) = p;
}

// batched [R,C] fp32 -> [C,R] bf16, with (l,h) output offset decomposition
__global__ void transpose_cvt(const float* __restrict__ in, bf16* __restrict__ out,
                              int R, int C, long inBatchStride, int subB,
                              long outStrideL, long outStrideH, long outOff) {
  __shared__ float tile[32][33];
  int bi = blockIdx.z;
  int l = bi / subB, h = bi - l * subB;
  const float* src = in + (size_t)bi * inBatchStride;
  bf16* dst = out + (size_t)l * outStrideL + (size_t)h * outStrideH + outOff;
  int r0 = blockIdx.y * 32, c0 = blockIdx.x * 32;
#pragma unroll
  for (int k = 0; k < 4; k++)
    tile[threadIdx.y + 8 * k][threadIdx.x] =
        src[(size_t)(r0 + threadIdx.y + 8 * k) * C + c0 + threadIdx.x];
  __syncthreads();
#pragma unroll
  for (int k = 0; k < 4; k++)
    dst[(size_t)(c0 + threadIdx.y + 8 * k) * R + r0 + threadIdx.x] =
        __float2bfloat16(tile[threadIdx.x][threadIdx.y + 8 * k]);
}

__global__ __launch_bounds__(256) void pack_qkv_bias(
    const float* __restrict__ bq, const float* __restrict__ bk,
    const float* __restrict__ bv, float* __restrict__ outb) {
  int i = blockIdx.x * 256 + threadIdx.x;
  if (i >= NLAYER * 3072) return;
  int l = i / 3072, r = i - l * 3072;
  int seg = r >> 10, n = r & 1023;
  const float* src = (seg == 0) ? bq : (seg == 1 ? bk : bv);
  outb[i] = src[l * 1024 + n];
}

// ---------------- embedding + positional encoding ----------------

__global__ __launch_bounds__(256) void embed_kernel(
    const int* __restrict__ idx, const float* __restrict__ emb, float* __restrict__ x) {
  int row = blockIdx.x;               // b*SEQ + s
  int s = row & (SEQ - 1);
  int token = idx[row];
  const float* e = emb + (size_t)token * DMODEL;
  float* xr = x + (size_t)row * DMODEL;
  int c = threadIdx.x * 4;
  float4 v = *(const float4*)(e + c);
  float o[4];
  const float vv[4] = {v.x, v.y, v.z, v.w};
#pragma unroll
  for (int u = 0; u < 4; u++) {
    int cc = c + u;
    int ii = cc >> 1;
    float div = expf((float)(2 * ii) * (-9.210340371976184f / 1024.f));
    float arg = (float)s * div;
    float pe = (cc & 1) ? cosf(arg) : sinf(arg);
    o[u] = vv[u] * 32.0f + pe;   // sqrt(1024)=32
  }
  *(float4*)(xr + c) = *(float4*)o;
}

// ---------------- layernorm (fp32 in, bf16 out) ----------------

__global__ __launch_bounds__(256) void ln_kernel(
    const float* __restrict__ x, const float* __restrict__ gs,
    const float* __restrict__ gb, bf16* __restrict__ out) {
  int row = blockIdx.x;
  const float* xr = x + (size_t)row * DMODEL;
  int c = threadIdx.x * 4;
  float4 v = *(const float4*)(xr + c);
  float s = v.x + v.y + v.z + v.w;
  float s2 = v.x * v.x + v.y * v.y + v.z * v.z + v.w * v.w;
#pragma unroll
  for (int off = 1; off < 64; off <<= 1) {
    s  += __shfl_xor(s, off, 64);
    s2 += __shfl_xor(s2, off, 64);
  }
  __shared__ float ps[4], ps2[4];
  int wave = threadIdx.x >> 6, lane = threadIdx.x & 63;
  if (lane == 0) { ps[wave] = s; ps2[wave] = s2; }
  __syncthreads();
  float ts = ps[0] + ps[1] + ps[2] + ps[3];
  float ts2 = ps2[0] + ps2[1] + ps2[2] + ps2[3];
  float mean = ts * (1.f / DMODEL);
  float var = ts2 * (1.f / DMODEL) - mean * mean;
  float rstd = rsqrtf(var + 1e-5f);
  const float vv[4] = {v.x, v.y, v.z, v.w};
  bf16x4v p;
#pragma unroll
  for (int u = 0; u < 4; u++) {
    float val = (vv[u] - mean) * rstd * gs[c + u] + gb[c + u];
    p[u] = (__bf16)val;
  }
  *(bf16x4v*)((__bf16*)out + (size_t)row * DMODEL + c) = p;
}

// ---------------- GEMM: C[M,N] = A[M,K] @ Wt[N,K]^T (+bias)(+resid)(+relu) ----------------
// R1 changes vs m97 structure:
//  - 1-D grid + bijective XCD chunking (m204) + B-panel-reuse-major (tm fastest) tile order:
//    consecutive blocks in an XCD chunk share a 256KB B-panel (L2) and cycle the small A (L3).
//  - "minimum 2-phase" pipeline (T3 recipe): issue next K-tile's global_load_lds BEFORE
//    ds_read+MFMA of the current tile; ONE barrier per K-step (its implicit vmcnt(0) drain
//    lands after the MFMA phase, so loads overlap compute). Explicit LDS double-buffer.
//  - BN template (128 or 64). BN=64 doubles the grid for N=1024 GEMMs (wo, w2):
//    256 blocks -> all 256 CUs active instead of 128.

template <int OUTBF, int RELU, int RESID, int BN>
__global__ __launch_bounds__(256) void gemm_bt(
    const bf16* __restrict__ A, const bf16* __restrict__ Wt,
    const float* __restrict__ bias, const float* __restrict__ resid,
    void* __restrict__ out, int M, int N, int K) {
  constexpr int NJ = BN / 32;          // n-fragments per wave (4 for BN=128, 2 for BN=64)
  __shared__ bf16 As[2][128 * 32];
  __shared__ bf16 Bs[2][BN * 32];
  const int tid = threadIdx.x;
  const int wave = tid >> 6, lane = tid & 63;
  const int lrow = lane & 15, quad = lane >> 4;
  const int wr = wave >> 1, wc = wave & 1;

  const int nbm = M >> 7;
  const int nbn = N / BN;
  const int nwg = nbm * nbn;
  // bijective XCD chunk swizzle (m204): xcd = orig%8 gets a contiguous chunk
  const int xcd = blockIdx.x & 7, local = blockIdx.x >> 3;
  const int q8 = nwg >> 3, r8 = nwg & 7;
  const int swz = (xcd < r8 ? xcd * (q8 + 1) : r8 * (q8 + 1) + (xcd - r8) * q8) + local;
  // tm fastest: consecutive blocks share the B-panel
  const int tm = (swz % nbm) * 128;
  const int tn = (swz / nbm) * BN;

  f32x4 acc[4][NJ] = {};

  auto STAGE = [&](int buf, int k0) {
#pragma unroll
    for (int j = 0; j < 2; j++) {            // A: 128 rows x 32 k
      int c = j * 256 + tid;
      int row = c >> 2, cp = c & 3;
      const bf16* ga = A + (size_t)(tm + row) * K + k0 + cp * 8;
      async_copy16(ga, (void*)(As[buf] + (j * 256 + wave * 64) * 8));
    }
#pragma unroll
    for (int j = 0; j < NJ / 2; j++) {       // B: BN rows x 32 k
      int c = j * 256 + tid;
      int row = c >> 2, cp = c & 3;
      const bf16* gb = Wt + (size_t)(tn + row) * K + k0 + cp * 8;
      async_copy16(gb, (void*)(Bs[buf] + (j * 256 + wave * 64) * 8));
    }
  };

  STAGE(0, 0);
  __syncthreads();            // drains vmcnt(0): tile 0 resident

  const int nk = K >> 5;
  int cur = 0;
  for (int kt = 0; kt < nk; ++kt) {
    if (kt + 1 < nk) STAGE(cur ^ 1, (kt + 1) << 5);   // next tile in flight during compute
    bf16x8 af[4], bfr[NJ];
#pragma unroll
    for (int i = 0; i < 4; i++)
      af[i] = *(const bf16x8*)(As[cur] + (wr * 64 + i * 16 + lrow) * 32 + quad * 8);
#pragma unroll
    for (int j = 0; j < NJ; j++)
      bfr[j] = *(const bf16x8*)(Bs[cur] + (wc * (NJ * 16) + j * 16 + lrow) * 32 + quad * 8);
#pragma unroll
    for (int i = 0; i < 4; i++)
#pragma unroll
      for (int j = 0; j < NJ; j++)
        acc[i][j] = __builtin_amdgcn_mfma_f32_16x16x32_bf16(af[i], bfr[j], acc[i][j], 0, 0, 0);
    __syncthreads();          // one barrier per K-step: drains this step's prefetch,
    cur ^= 1;                 // and fences everyone's ds_reads before next STAGE overwrite
  }

#pragma unroll
  for (int i = 0; i < 4; i++) {
#pragma unroll
    for (int j = 0; j < NJ; j++) {
#pragma unroll
      for (int r = 0; r < 4; r++) {
        int grow = tm + wr * 64 + i * 16 + quad * 4 + r;
        int gcol = tn + wc * (NJ * 16) + j * 16 + lrow;
        float v = acc[i][j][r];
        if (bias) v += bias[gcol];
        if (RESID) v += resid[(size_t)grow * N + gcol];
        if (RELU) v = fmaxf(v, 0.f);
        if (OUTBF) ((bf16*)out)[(size_t)grow * N + gcol] = __float2bfloat16(v);
        else       ((float*)out)[(size_t)grow * N + gcol] = v;
      }
    }
  }
}

// ---------------- flash attention (causal), qkv [B,S,3072] bf16 -> o [B,S,1024] bf16 ----

__global__ __launch_bounds__(256) void attn_kernel(
    const bf16* __restrict__ qkv, bf16* __restrict__ o) {
  __shared__ bf16 Qs[64 * 64];
  __shared__ bf16 Ks[64 * 64];
  __shared__ bf16 Vt[64 * 64];  // transposed: [e][kv]
  __shared__ bf16 Ps[64 * 64];
  int qt = blockIdx.x;
  int bh = blockIdx.y;
  int b = bh >> 4, h = bh & 15;
  int tid = threadIdx.x;
  int wave = tid >> 6, lane = tid & 63;
  int lrow = lane & 15, quad = lane >> 4;
  const size_t rs = 3072;
  const bf16* qb = qkv + ((size_t)b * SEQ + qt * 64) * rs + h * 64;
#pragma unroll
  for (int j = 0; j < 2; j++) {
    int c = j * 256 + tid;
    int r = c >> 3, cp = c & 7;
    *(uint4*)((__bf16*)Qs + r * 64 + cp * 8) = *(const uint4*)((const __bf16*)qb + (size_t)r * rs + cp * 8);
  }
  float m_i[4], l_i[4];
  f32x4 acc_o[4] = {};
#pragma unroll
  for (int r = 0; r < 4; r++) { m_i[r] = -1e30f; l_i[r] = 0.f; }

  for (int kt = 0; kt <= qt; kt++) {
    const bf16* kb = qkv + ((size_t)b * SEQ + kt * 64) * rs + 1024 + h * 64;
    const bf16* vb = qkv + ((size_t)b * SEQ + kt * 64) * rs + 2048 + h * 64;
    __syncthreads();  // protect Ks/Vt from previous iteration's MFMA reads
#pragma unroll
    for (int j = 0; j < 2; j++) {
      int c = j * 256 + tid;
      int r = c >> 3, cp = c & 7;
      *(uint4*)((__bf16*)Ks + r * 64 + cp * 8) = *(const uint4*)((const __bf16*)kb + (size_t)r * rs + cp * 8);
      uint4 vv = *(const uint4*)((const __bf16*)vb + (size_t)r * rs + cp * 8);
      const bf16* ve = (const bf16*)&vv;
#pragma unroll
      for (int e = 0; e < 8; e++) Vt[(cp * 8 + e) * 64 + r] = ve[e];
    }
    __syncthreads();
    f32x4 sc[4] = {};
#pragma unroll
    for (int ks = 0; ks < 2; ks++) {
      bf16x8 aq = *(const bf16x8*)((__bf16*)Qs + (wave * 16 + lrow) * 64 + ks * 32 + quad * 8);
#pragma unroll
      for (int j = 0; j < 4; j++) {
        bf16x8 bk = *(const bf16x8*)((__bf16*)Ks + (j * 16 + lrow) * 64 + ks * 32 + quad * 8);
        sc[j] = __builtin_amdgcn_mfma_f32_16x16x32_bf16(aq, bk, sc[j], 0, 0, 0);
      }
    }
    int grow_base = qt * 64 + wave * 16 + quad * 4;
    bool diag = (kt == qt);
#pragma unroll
    for (int r = 0; r < 4; r++) {
      int grow = grow_base + r;
      float mx = -1e30f;
#pragma unroll
      for (int j = 0; j < 4; j++) {
        float v = sc[j][r] * 0.125f;  // 1/sqrt(64)
        if (diag) { int gcol = kt * 64 + j * 16 + lrow; if (gcol > grow) v = -1e30f; }
        sc[j][r] = v;
        mx = fmaxf(mx, v);
      }
#pragma unroll
      for (int off = 1; off < 16; off <<= 1) mx = fmaxf(mx, __shfl_xor(mx, off, 64));
      float mnew = fmaxf(m_i[r], mx);
      float alpha = __expf(m_i[r] - mnew);
      float rsum = 0.f;
#pragma unroll
      for (int j = 0; j < 4; j++) {
        float p = __expf(sc[j][r] - mnew);
        sc[j][r] = p;
        rsum += p;
      }
#pragma unroll
      for (int off = 1; off < 16; off <<= 1) rsum += __shfl_xor(rsum, off, 64);
      l_i[r] = l_i[r] * alpha + rsum;
      m_i[r] = mnew;
#pragma unroll
      for (int j = 0; j < 4; j++) acc_o[j][r] *= alpha;
    }
#pragma unroll
    for (int j = 0; j < 4; j++)
#pragma unroll
      for (int r = 0; r < 4; r++)
        Ps[(wave * 16 + quad * 4 + r) * 64 + j * 16 + lrow] = __float2bfloat16(sc[j][r]);
    __syncthreads();
#pragma unroll
    for (int ks = 0; ks < 2; ks++) {
      bf16x8 ap = *(const bf16x8*)((__bf16*)Ps + (wave * 16 + lrow) * 64 + ks * 32 + quad * 8);
#pragma unroll
      for (int j = 0; j < 4; j++) {
        bf16x8 bv = *(const bf16x8*)((__bf16*)Vt + (j * 16 + lrow) * 64 + ks * 32 + quad * 8);
        acc_o[j] = __builtin_amdgcn_mfma_f32_16x16x32_bf16(ap, bv, acc_o[j], 0, 0, 0);
      }
    }
  }
#pragma unroll
  for (int r = 0; r < 4; r++) {
    float inv = 1.f / l_i[r];
    int grow = qt * 64 + wave * 16 + quad * 4 + r;
#pragma unroll
    for (int j = 0; j < 4; j++) {
      int e = j * 16 + lrow;
      o[((size_t)b * SEQ + grow) * DMODEL + h * 64 + e] = __float2bfloat16(acc_o[j][r] * inv);
    }
  }
}

// ---------------- launcher ----------------

extern "C" void kernel_launch(void* const* d_in, const int* in_sizes, int n_in,
                              void* d_out, int out_size, void* d_ws, size_t ws_size,
                              hipStream_t stream) {
  const int*   idx   = (const int*)d_in[0];
  const float* emb   = (const float*)d_in[1];
  const float* cls_b = (const float*)d_in[2];
  const float* ln1_s = (const float*)d_in[3];
  const float* ln1_b = (const float*)d_in[4];
  const float* wq    = (const float*)d_in[5];
  const float* bq    = (const float*)d_in[6];
  const float* wk    = (const float*)d_in[7];
  const float* bk    = (const float*)d_in[8];
  const float* wv    = (const float*)d_in[9];
  const float* bv    = (const float*)d_in[10];
  const float* wo    = (const float*)d_in[11];
  const float* bo    = (const float*)d_in[12];
  const float* ln2_s = (const float*)d_in[13];
  const float* ln2_b = (const float*)d_in[14];
  const float* w1    = (const float*)d_in[15];
  const float* b1    = (const float*)d_in[16];
  const float* w2    = (const float*)d_in[17];
  const float* b2    = (const float*)d_in[18];
  const float* lnf_s = (const float*)d_in[19];
  const float* lnf_b = (const float*)d_in[20];
  float* out = (float*)d_out;

  char* ws = (char*)d_ws;
  bf16* emb_bf = (bf16*)ws;  ws += (size_t)VOCAB * DMODEL * 2;
  bf16* wqkv_t = (bf16*)ws;  ws += (size_t)NLAYER * 3072 * 1024 * 2;
  float* bqkv  = (float*)ws; ws += (size_t)NLAYER * 3072 * 4;
  bf16* wo_t   = (bf16*)ws;  ws += (size_t)NLAYER * 1024 * 1024 * 2;
  bf16* w1_t   = (bf16*)ws;  ws += (size_t)NLAYER * 4096 * 1024 * 2;
  bf16* w2_t   = (bf16*)ws;  ws += (size_t)NLAYER * 1024 * 4096 * 2;
  float* x     = (float*)ws; ws += (size_t)MTOK * DMODEL * 4;
  bf16* hbuf   = (bf16*)ws;  ws += (size_t)MTOK * DMODEL * 2;
  bf16* qkvb   = (bf16*)ws;  ws += (size_t)MTOK * 3072 * 2;
  bf16* obuf   = (bf16*)ws;  ws += (size_t)MTOK * DMODEL * 2;
  bf16* midb   = (bf16*)ws;  ws += (size_t)MTOK * DFF_ * 2;

  // weight prep (every call: ws is re-poisoned by harness)
  convert_bf16_kernel<<<(VOCAB * DMODEL) / 1024, 256, 0, stream>>>(emb, emb_bf, (long)VOCAB * DMODEL);
  dim3 tb(32, 8);
  for (int sel = 0; sel < 3; sel++) {
    const float* src = (sel == 0) ? wq : (sel == 1 ? wk : wv);
    transpose_cvt<<<dim3(64 / 32, 1024 / 32, NLAYER * NHEAD), tb, 0, stream>>>(
        src, wqkv_t, 1024, 64, (long)1024 * 64, NHEAD,
        (long)3072 * 1024, (long)64 * 1024, (long)sel * 1024 * 1024);
  }
  pack_qkv_bias<<<(NLAYER * 3072 + 255) / 256, 256, 0, stream>>>(bq, bk, bv, bqkv);
  transpose_cvt<<<dim3(1024 / 32, 1024 / 32, NLAYER), tb, 0, stream>>>(
      wo, wo_t, 1024, 1024, (long)1024 * 1024, 1, (long)1024 * 1024, 0, 0);
  transpose_cvt<<<dim3(4096 / 32, 1024 / 32, NLAYER), tb, 0, stream>>>(
      w1, w1_t, 1024, 4096, (long)1024 * 4096, 1, (long)4096 * 1024, 0, 0);
  transpose_cvt<<<dim3(1024 / 32, 4096 / 32, NLAYER), tb, 0, stream>>>(
      w2, w2_t, 4096, 1024, (long)4096 * 1024, 1, (long)1024 * 4096, 0, 0);

  embed_kernel<<<MTOK, 256, 0, stream>>>(idx, emb, x);

  const int nbm = MTOK / 128;
  for (int l = 0; l < NLAYER; l++) {
    ln_kernel<<<MTOK, 256, 0, stream>>>(x, ln1_s + l * 1024, ln1_b + l * 1024, hbuf);
    gemm_bt<1, 0, 0, 128><<<dim3(nbm * (3072 / 128)), 256, 0, stream>>>(
        hbuf, wqkv_t + (size_t)l * 3072 * 1024, bqkv + l * 3072, nullptr, qkvb, MTOK, 3072, 1024);
    attn_kernel<<<dim3(SEQ / 64, BATCH * NHEAD), 256, 0, stream>>>(qkvb, obuf);
    gemm_bt<0, 0, 1, 64><<<dim3(nbm * (1024 / 64)), 256, 0, stream>>>(
        obuf, wo_t + (size_t)l * 1024 * 1024, bo + l * 1024, x, x, MTOK, 1024, 1024);
    ln_kernel<<<MTOK, 256, 0, stream>>>(x, ln2_s + l * 1024, ln2_b + l * 1024, hbuf);
    gemm_bt<1, 1, 0, 128><<<dim3(nbm * (4096 / 128)), 256, 0, stream>>>(
        hbuf, w1_t + (size_t)l * 4096 * 1024, b1 + l * 4096, nullptr, midb, MTOK, 4096, 1024);
    gemm_bt<0, 0, 1, 64><<<dim3(nbm * (1024 / 64)), 256, 0, stream>>>(
        midb, w2_t + (size_t)l * 1024 * 4096, b2 + l * 1024, x, x, MTOK, 1024, 4096);
  }
  ln_kernel<<<MTOK, 256, 0, stream>>>(x, lnf_s, lnf_b, hbuf);
  gemm_bt<0, 0, 0, 128><<<dim3(nbm * (VOCAB / 128)), 256, 0, stream>>>(
      hbuf, emb_bf, cls_b, nullptr, out, MTOK, VOCAB, 1024);
}